// Round 1
// 192.345 us; speedup vs baseline: 1.0001x; 1.0001x over previous
//
#include <hip/hip_runtime.h>
#include <hip/hip_bf16.h>

#define FDIM 64
#define BNODES 64          // nodes per bucket (dst >> 6)
#define CHUNK 4096         // edges per partition chunk (196 chunks -> measured optimum)
#define HP 72              // padded LDS row stride in shorts
#define GCAP 2048          // staged capacity (bucket mean 1023, sigma 32 -> huge margin)

typedef short bf16x8 __attribute__((ext_vector_type(8)));
typedef float f32x4 __attribute__((ext_vector_type(4)));

__device__ __forceinline__ unsigned short f2bf(float f) {
    unsigned int u = __float_as_uint(f);
    unsigned int r = (u + 0x7fffu + ((u >> 16) & 1u)) >> 16;   // RNE
    return (unsigned short)r;
}
__device__ __forceinline__ float bflo(unsigned int p) { return __uint_as_float(p << 16); }
__device__ __forceinline__ float bfhi(unsigned int p) { return __uint_as_float(p & 0xffff0000u); }

// ---- fused: cast features (blocks [0,ncast)) + transpose 6 weight matrices
// (blocks [ncast,ncast+6)) + per-chunk bucket histogram (blocks [ncast+6, ...)) ----
__global__ __launch_bounds__(256) void cast_prep_hist(const float* __restrict__ x,
                                                      unsigned short* __restrict__ xb, int n4,
                                                      int ncast,
                                                      const float* __restrict__ W10,
                                                      const float* __restrict__ W20,
                                                      const float* __restrict__ W11,
                                                      const float* __restrict__ W21,
                                                      const float* __restrict__ W12,
                                                      const float* __restrict__ W22,
                                                      unsigned short* __restrict__ wt,
                                                      const int* __restrict__ dst,
                                                      int* __restrict__ hist,
                                                      int n_edges, int nbuck) {
    int tid = threadIdx.x;
    if (blockIdx.x < (unsigned)ncast) {
        int i = blockIdx.x * 256 + tid;
        if (i < n4) {
            float4 v = ((const float4*)x)[i];
            uint2 o;
            o.x = (unsigned int)f2bf(v.x) | ((unsigned int)f2bf(v.y) << 16);
            o.y = (unsigned int)f2bf(v.z) | ((unsigned int)f2bf(v.w) << 16);
            ((uint2*)xb)[i] = o;
        }
        return;
    }
    if (blockIdx.x < (unsigned)(ncast + 6)) {
        __shared__ unsigned short s[64 * 64];
        int wsel = blockIdx.x - ncast;     // 0..5
        const float* W;
        switch (wsel) {
            case 0: W = W10; break;
            case 1: W = W20; break;
            case 2: W = W11; break;
            case 3: W = W21; break;
            case 4: W = W12; break;
            default: W = W22; break;
        }
#pragma unroll
        for (int p = 0; p < 4; p++) {
            int idx = tid + p * 256;          // 0..1023
            int k = idx >> 4;
            int n0 = (idx & 15) * 4;
            float4 v = ((const float4*)W)[idx];
            s[(n0 + 0) * 64 + k] = f2bf(v.x);
            s[(n0 + 1) * 64 + k] = f2bf(v.y);
            s[(n0 + 2) * 64 + k] = f2bf(v.z);
            s[(n0 + 3) * 64 + k] = f2bf(v.w);
        }
        __syncthreads();
        uint4* o = (uint4*)(wt + (size_t)wsel * 4096);
#pragma unroll
        for (int p = 0; p < 2; p++) {
            int idx = tid + p * 256;          // 0..511
            o[idx] = ((uint4*)s)[idx];
        }
        return;
    }
    // histogram branch
    {
        __shared__ int lh[1024];
        int chunk = blockIdx.x - ncast - 6;
        for (int i = tid; i < nbuck; i += 256) lh[i] = 0;
        __syncthreads();
        int beg = chunk * CHUNK;
        int end = min(beg + CHUNK, n_edges);
        for (int e = beg + tid; e < end; e += 256)
            atomicAdd(&lh[dst[e] >> 6], 1);
        __syncthreads();
        for (int i = tid; i < nbuck; i += 256)
            hist[(size_t)chunk * nbuck + i] = lh[i];
    }
}

// ---- pass 2a: per-bucket exclusive scan over chunks (nchunks <= 256) ----
__global__ __launch_bounds__(256) void scan_chunks(const int* __restrict__ hist,
                                                   int* __restrict__ chunk_off,
                                                   int* __restrict__ bucket_total,
                                                   int nchunks, int nbuck) {
    __shared__ int s[256];
    int b = blockIdx.x;
    int t = threadIdx.x;
    int v = (t < nchunks) ? hist[(size_t)t * nbuck + b] : 0;
    s[t] = v;
    __syncthreads();
    for (int off = 1; off < 256; off <<= 1) {
        int u = (t >= off) ? s[t - off] : 0;
        __syncthreads();
        s[t] += u;
        __syncthreads();
    }
    if (t < nchunks) chunk_off[(size_t)t * nbuck + b] = s[t] - v;  // exclusive
    if (t == 255) bucket_total[b] = s[255];
}

// ---- pass 2b: exclusive scan of bucket totals ----
__global__ __launch_bounds__(1024) void scan_buckets(const int* __restrict__ bucket_total,
                                                     int* __restrict__ bucket_start,
                                                     int* __restrict__ row_ptr,
                                                     int nbuck, int n_nodes, int n_edges) {
    __shared__ int s[1024];
    int t = threadIdx.x;
    int v = (t < nbuck) ? bucket_total[t] : 0;
    s[t] = v;
    __syncthreads();
    for (int off = 1; off < 1024; off <<= 1) {
        int u = (t >= off) ? s[t - off] : 0;
        __syncthreads();
        s[t] += u;
        __syncthreads();
    }
    if (t < nbuck) bucket_start[t] = s[t] - v;
    if (t == 0) { bucket_start[nbuck] = n_edges; row_ptr[n_nodes] = n_edges; }
}

// ---- pass 3: fill packed edges, (chunk,bucket)-contiguous runs ----
__global__ __launch_bounds__(256) void bucket_fill(const int* __restrict__ src,
                                                   const int* __restrict__ dst,
                                                   const int* __restrict__ bucket_start,
                                                   const int* __restrict__ chunk_off,
                                                   unsigned int* __restrict__ packed,
                                                   int n_edges, int nbuck) {
    __shared__ int cur[1024];
    int chunk = blockIdx.x;
    for (int i = threadIdx.x; i < nbuck; i += 256)
        cur[i] = bucket_start[i] + chunk_off[(size_t)chunk * nbuck + i];
    __syncthreads();
    int beg = chunk * CHUNK;
    int end = min(beg + CHUNK, n_edges);
    for (int e = beg + threadIdx.x; e < end; e += 256) {
        int d = dst[e];
        int b = d >> 6;
        int pos = atomicAdd(&cur[b], 1);
        packed[pos] = (unsigned int)src[e] | ((unsigned int)(d & 63) << 16);
    }
}

// ---- fused conv: (optional in-LDS sort) + gather + MFMA MLP (+ optional final linear) ----
// One block per 64-node bucket. 256 threads.
//  SORT mode   (conv 1): sort bucket edges to node granularity in LDS, emit
//                        row_ptr + src_sorted for later convs, gather from sidx.
//  NOSORT mode (convs 2,3): stage sidx from src_sorted via row_ptr.
// Then: acc[16] fp32 per lane (4 lanes/node) -> bf16 into sH -> 2-layer MFMA MLP
// with B-fragments loaded directly from global (L1-hot, identical across blocks).
#define ACCUM(v0, v1)                                          \
    acc[0] += bflo((v0).x); acc[1] += bfhi((v0).x);            \
    acc[2] += bflo((v0).y); acc[3] += bfhi((v0).y);            \
    acc[4] += bflo((v0).z); acc[5] += bfhi((v0).z);            \
    acc[6] += bflo((v0).w); acc[7] += bfhi((v0).w);            \
    acc[8] += bflo((v1).x); acc[9] += bfhi((v1).x);            \
    acc[10] += bflo((v1).y); acc[11] += bfhi((v1).y);          \
    acc[12] += bflo((v1).z); acc[13] += bfhi((v1).z);          \
    acc[14] += bflo((v1).w); acc[15] += bfhi((v1).w);

__global__ __launch_bounds__(256) void conv_fused(
        const unsigned short* __restrict__ xb,
        const unsigned int* __restrict__ packed,
        const int* __restrict__ bucket_start,
        int* __restrict__ src_sorted,
        int* __restrict__ row_ptr,
        const unsigned short* __restrict__ wt1, const float* __restrict__ b1,
        const unsigned short* __restrict__ wt2, const float* __restrict__ b2,
        const float* __restrict__ Wl, const float* __restrict__ bl,
        unsigned short* __restrict__ y, float* __restrict__ out,
        int n_nodes, int do_sort, int do_final) {
    // 16 KB union: [spk GCAP u32][sidx GCAP i32] during sort/gather; sH [64][HP] bf16 after.
    __shared__ __align__(16) unsigned char ubuf[16384];
    unsigned int* spk = (unsigned int*)ubuf;
    int* sidx = (int*)(ubuf + 8192);
    unsigned short* sH = (unsigned short*)ubuf;
    __shared__ int cnt[BNODES], nbeg[BNODES], cur[BNODES];
    __shared__ float sWl[FDIM * 10];
    __shared__ float sbl[16];

    int b = blockIdx.x;
    int tid = threadIdx.x;
    int base = b * BNODES;

    if (do_final) {
        for (int i = tid; i < FDIM * 10; i += 256) sWl[i] = Wl[i];
        if (tid < 10) sbl[tid] = bl[tid];
    }

    int nl = tid >> 2;                 // node-local 0..63 (4 lanes/node)
    int node = base + nl;
    bool valid = node < n_nodes;
    int q = (tid & 3) * 16;            // short column base: 16 bf16 = 32 B per lane

    int ebeg, total, dbeg = 0, dcnt = 0;
    bool fits;

    if (do_sort) {
        ebeg = bucket_start[b];
        int eend = bucket_start[b + 1];
        total = eend - ebeg;
        fits = (total <= GCAP);
        if (tid < BNODES) cnt[tid] = 0;
        if (fits)
            for (int i = tid; i < total; i += 256) spk[i] = packed[ebeg + i];
        __syncthreads();
        if (fits) {
            for (int i = tid; i < total; i += 256) atomicAdd(&cnt[spk[i] >> 16], 1);
        } else {
            for (int e = ebeg + tid; e < eend; e += 256) atomicAdd(&cnt[packed[e] >> 16], 1);
        }
        __syncthreads();
        if (tid < 64) {                // wave 0: shfl inclusive scan over 64 degrees
            int v = cnt[tid];
            int inc = v;
#pragma unroll
            for (int off = 1; off < 64; off <<= 1) {
                int u = __shfl_up(inc, off, 64);
                if (tid >= off) inc += u;
            }
            int ex = inc - v;
            nbeg[tid] = ex;
            cur[tid] = ex;
            int nd = base + tid;
            if (nd < n_nodes) row_ptr[nd] = ebeg + ex;
        }
        __syncthreads();
        if (fits) {
            for (int i = tid; i < total; i += 256) {
                unsigned int p = spk[i];
                int pos = atomicAdd(&cur[p >> 16], 1);
                int s = (int)(p & 0xFFFFu);
                sidx[pos] = s;
                src_sorted[ebeg + pos] = s;      // for convs 2/3
            }
        } else {
            for (int e = ebeg + tid; e < eend; e += 256) {
                unsigned int p = packed[e];
                int pos = atomicAdd(&cur[p >> 16], 1);
                src_sorted[ebeg + pos] = (int)(p & 0xFFFFu);
            }
        }
        __syncthreads();               // sorted indices visible block-wide (LDS or global)
        dbeg = nbeg[nl];
        dcnt = cnt[nl];
    } else {
        ebeg = row_ptr[base];
        int eend = row_ptr[min(base + BNODES, n_nodes)];
        total = eend - ebeg;
        fits = (total <= GCAP);
        int stage = fits ? total : GCAP;
        for (int i = tid; i < stage; i += 256) sidx[i] = src_sorted[ebeg + i];
        int rb = valid ? row_ptr[node] : ebeg;
        int re = valid ? row_ptr[node + 1] : ebeg;
        dbeg = rb - ebeg;
        dcnt = re - rb;
        __syncthreads();
    }

    int dend = dbeg + dcnt;
    int dmid;                          // [dbeg,dmid) from LDS sidx; [dmid,dend) from global
    if (fits) dmid = dend;
    else if (do_sort) dmid = dbeg;     // nothing staged in SORT overflow path
    else dmid = min(dend, GCAP);

    // ---- gather: self row + neighbor rows, fp32 accumulate ----
    float acc[16];
    if (valid) {
        const uint4* xr = (const uint4*)(xb + (size_t)node * FDIM + q);
        uint4 v0 = xr[0], v1 = xr[1];
        acc[0] = bflo(v0.x); acc[1] = bfhi(v0.x);
        acc[2] = bflo(v0.y); acc[3] = bfhi(v0.y);
        acc[4] = bflo(v0.z); acc[5] = bfhi(v0.z);
        acc[6] = bflo(v0.w); acc[7] = bfhi(v0.w);
        acc[8] = bflo(v1.x); acc[9] = bfhi(v1.x);
        acc[10] = bflo(v1.y); acc[11] = bfhi(v1.y);
        acc[12] = bflo(v1.z); acc[13] = bfhi(v1.z);
        acc[14] = bflo(v1.w); acc[15] = bfhi(v1.w);
    } else {
#pragma unroll
        for (int i = 0; i < 16; i++) acc[i] = 0.f;
    }

    int e = dbeg;
    for (; e + 3 < dmid; e += 4) {
        int s[4];
#pragma unroll
        for (int j = 0; j < 4; j++) s[j] = sidx[e + j];
        uint4 va[4], vb[4];
#pragma unroll
        for (int j = 0; j < 4; j++) {
            const uint4* p = (const uint4*)(xb + (size_t)s[j] * FDIM + q);
            va[j] = p[0];
            vb[j] = p[1];
        }
#pragma unroll
        for (int j = 0; j < 4; j++) { ACCUM(va[j], vb[j]); }
    }
    for (; e < dmid; e++) {
        const uint4* p = (const uint4*)(xb + (size_t)sidx[e] * FDIM + q);
        uint4 v0 = p[0], v1 = p[1];
        ACCUM(v0, v1);
    }
    for (; e < dend; e++) {            // overflow tail / SORT-overflow full path
        const uint4* p = (const uint4*)(xb + (size_t)src_sorted[ebeg + e] * FDIM + q);
        uint4 v0 = p[0], v1 = p[1];
        ACCUM(v0, v1);
    }

    __syncthreads();                   // sidx/spk dead -> ubuf becomes sH

    {
        uint4 p0, p1;
        p0.x = (unsigned int)f2bf(acc[0]) | ((unsigned int)f2bf(acc[1]) << 16);
        p0.y = (unsigned int)f2bf(acc[2]) | ((unsigned int)f2bf(acc[3]) << 16);
        p0.z = (unsigned int)f2bf(acc[4]) | ((unsigned int)f2bf(acc[5]) << 16);
        p0.w = (unsigned int)f2bf(acc[6]) | ((unsigned int)f2bf(acc[7]) << 16);
        p1.x = (unsigned int)f2bf(acc[8]) | ((unsigned int)f2bf(acc[9]) << 16);
        p1.y = (unsigned int)f2bf(acc[10]) | ((unsigned int)f2bf(acc[11]) << 16);
        p1.z = (unsigned int)f2bf(acc[12]) | ((unsigned int)f2bf(acc[13]) << 16);
        p1.w = (unsigned int)f2bf(acc[14]) | ((unsigned int)f2bf(acc[15]) << 16);
        *(uint4*)(&sH[nl * HP + q]) = p0;
        *(uint4*)(&sH[nl * HP + q + 8]) = p1;
    }
    __syncthreads();

    // ---- MFMA MLP; B-fragments straight from global (identical across blocks, L1-hot) ----
    int w = tid >> 6;       // wave id 0..3
    int lane = tid & 63;
    int qd = lane >> 4;     // quad 0..3
    int m = lane & 15;
    int arow = (w * 16 + m) * HP;

    f32x4 a4[4];

    // layer 1: G = relu(H @ W1 + b1)
    {
        bf16x8 a0 = *(bf16x8*)(&sH[arow + qd * 8]);
        bf16x8 a1 = *(bf16x8*)(&sH[arow + 32 + qd * 8]);
#pragma unroll
        for (int t = 0; t < 4; t++) {
            float bias = b1[t * 16 + m];
            a4[t] = (f32x4){bias, bias, bias, bias};
            bf16x8 bA = *(const bf16x8*)(wt1 + (size_t)(t * 16 + m) * FDIM + qd * 8);
            bf16x8 bB = *(const bf16x8*)(wt1 + (size_t)(t * 16 + m) * FDIM + 32 + qd * 8);
            a4[t] = __builtin_amdgcn_mfma_f32_16x16x32_bf16(a0, bA, a4[t], 0, 0, 0);
            a4[t] = __builtin_amdgcn_mfma_f32_16x16x32_bf16(a1, bB, a4[t], 0, 0, 0);
        }
#pragma unroll
        for (int t = 0; t < 4; t++)
#pragma unroll
            for (int r = 0; r < 4; r++)
                sH[(w * 16 + qd * 4 + r) * HP + t * 16 + m] = f2bf(fmaxf(a4[t][r], 0.f));
    }

    // layer 2: O = relu(G @ W2 + b2)
    {
        bf16x8 a0 = *(bf16x8*)(&sH[arow + qd * 8]);
        bf16x8 a1 = *(bf16x8*)(&sH[arow + 32 + qd * 8]);
#pragma unroll
        for (int t = 0; t < 4; t++) {
            float bias = b2[t * 16 + m];
            a4[t] = (f32x4){bias, bias, bias, bias};
            bf16x8 bA = *(const bf16x8*)(wt2 + (size_t)(t * 16 + m) * FDIM + qd * 8);
            bf16x8 bB = *(const bf16x8*)(wt2 + (size_t)(t * 16 + m) * FDIM + 32 + qd * 8);
            a4[t] = __builtin_amdgcn_mfma_f32_16x16x32_bf16(a0, bA, a4[t], 0, 0, 0);
            a4[t] = __builtin_amdgcn_mfma_f32_16x16x32_bf16(a1, bB, a4[t], 0, 0, 0);
        }
#pragma unroll
        for (int t = 0; t < 4; t++)
#pragma unroll
            for (int r = 0; r < 4; r++)
                sH[(w * 16 + qd * 4 + r) * HP + t * 16 + m] = f2bf(fmaxf(a4[t][r], 0.f));
    }
    __syncthreads();

    if (!do_final) {
#pragma unroll
        for (int p = 0; p < 2; p++) {
            int idx = tid + p * 256;
            int r = idx >> 3, qq = idx & 7;
            if (base + r < n_nodes)
                *(uint4*)(y + (size_t)(base + r) * FDIM + qq * 8) = *(uint4*)(&sH[r * HP + qq * 8]);
        }
    } else {
        for (int i = tid; i < 64 * 10; i += 256) {
            int n2 = i / 10, cc = i % 10;
            int nd = base + n2;
            if (nd < n_nodes) {
                float s = sbl[cc];
#pragma unroll
                for (int k0 = 0; k0 < FDIM; k0 += 4) {
                    uint2 hp = *(uint2*)(&sH[n2 * HP + k0]);
                    s += bflo(hp.x) * sWl[(k0 + 0) * 10 + cc] + bfhi(hp.x) * sWl[(k0 + 1) * 10 + cc]
                       + bflo(hp.y) * sWl[(k0 + 2) * 10 + cc] + bfhi(hp.y) * sWl[(k0 + 3) * 10 + cc];
                }
                out[(size_t)nd * 10 + cc] = s;
            }
        }
    }
}

extern "C" void kernel_launch(void* const* d_in, const int* in_sizes, int n_in,
                              void* d_out, int out_size, void* d_ws, size_t ws_size,
                              hipStream_t stream) {
    const float* features = (const float*)d_in[0];
    const int* edges = (const int*)d_in[1];
    int n_nodes = in_sizes[0] / FDIM;          // 50000
    int n_edges = in_sizes[1] / 2;             // 800000
    const int* src = edges;
    const int* dst = edges + n_edges;

    int nbuck = (n_nodes + BNODES - 1) / BNODES;     // 782
    int nchunks = (n_edges + CHUNK - 1) / CHUNK;     // 196

    // workspace: hist | chunk_off | bucket_total | bucket_start | row_ptr | packed | src_sorted | bf16 bufs | wt
    int* hist = (int*)d_ws;
    int* chunk_off = hist + (size_t)nchunks * nbuck;
    int* bucket_total = chunk_off + (size_t)nchunks * nbuck;
    int* bucket_start = bucket_total + nbuck;
    int* row_ptr = bucket_start + nbuck + 1;
    unsigned int* packed = (unsigned int*)(row_ptr + n_nodes + 1);
    int* src_sorted = (int*)(packed + n_edges);
    size_t int_elems = 2 * (size_t)nchunks * nbuck + 2 * (size_t)nbuck + 2
                       + (size_t)n_nodes + 2 * (size_t)n_edges;
    int_elems = (int_elems + 3) & ~(size_t)3;
    size_t buf_elems = (size_t)n_nodes * FDIM;
    unsigned short* hb  = (unsigned short*)((int*)d_ws + int_elems);  // unused now (kept for layout stability)
    unsigned short* xb0 = hb + buf_elems;
    unsigned short* yA  = xb0 + buf_elems;
    unsigned short* yB  = yA + buf_elems;
    unsigned short* wt  = yB + buf_elems;     // 6 * 4096 bf16 (48 KB)
    (void)hb;

    dim3 bs(256);
    int n4 = (int)(buf_elems / 4);
    int ncast = (n4 + 255) / 256;          // 3125
    dim3 gs_cph(ncast + 6 + nchunks);      // cast + weight-prep + histogram, one launch

    // --- fused cast + weight prep + histogram ---
    cast_prep_hist<<<gs_cph, bs, 0, stream>>>(features, xb0, n4, ncast,
                                              (const float*)d_in[2], (const float*)d_in[4],
                                              (const float*)d_in[6], (const float*)d_in[8],
                                              (const float*)d_in[10], (const float*)d_in[12], wt,
                                              dst, hist, n_edges, nbuck);

    // --- build node-grouped CSR ---
    scan_chunks<<<nbuck, 256, 0, stream>>>(hist, chunk_off, bucket_total, nchunks, nbuck);
    scan_buckets<<<1, 1024, 0, stream>>>(bucket_total, bucket_start, row_ptr, nbuck, n_nodes, n_edges);
    bucket_fill<<<nchunks, 256, 0, stream>>>(src, dst, bucket_start, chunk_off, packed, n_edges, nbuck);

    const float* Wl = (const float*)d_in[14];
    const float* bl = (const float*)d_in[15];

    // --- conv 1: fused sort + gather + MLP (emits row_ptr/src_sorted for convs 2,3) ---
    conv_fused<<<nbuck, bs, 0, stream>>>(xb0, packed, bucket_start, src_sorted, row_ptr,
                                         wt, (const float*)d_in[3],
                                         wt + 4096, (const float*)d_in[5],
                                         Wl, bl, yA, (float*)d_out, n_nodes, 1, 0);

    // --- conv 2: fused gather + MLP ---
    conv_fused<<<nbuck, bs, 0, stream>>>(yA, packed, bucket_start, src_sorted, row_ptr,
                                         wt + 2 * 4096, (const float*)d_in[7],
                                         wt + 3 * 4096, (const float*)d_in[9],
                                         Wl, bl, yB, (float*)d_out, n_nodes, 0, 0);

    // --- conv 3: fused gather + MLP + final linear ---
    conv_fused<<<nbuck, bs, 0, stream>>>(yB, packed, bucket_start, src_sorted, row_ptr,
                                         wt + 4 * 4096, (const float*)d_in[11],
                                         wt + 5 * 4096, (const float*)d_in[13],
                                         Wl, bl, yA, (float*)d_out, n_nodes, 0, 1);
}